// Round 4
// baseline (315.664 us; speedup 1.0000x reference)
//
#include <hip/hip_runtime.h>
#include <hip/hip_bf16.h>
#include <cstdint>
#include <cstddef>

typedef __bf16 bf16x8 __attribute__((ext_vector_type(8)));
typedef float  f32x4  __attribute__((ext_vector_type(4)));
typedef unsigned short us8 __attribute__((ext_vector_type(8)));

__device__ __forceinline__ unsigned short f2bf(float f) {
    __hip_bfloat16 b = __float2bfloat16(f);
    return *reinterpret_cast<unsigned short*>(&b);
}

// fast GELU (tanh form), ~7 VALU ops, saturation-safe:
// g = x / (1 + exp2(x*(-2.30220795 - 0.10294314 x^2)))
__device__ __forceinline__ float fast_gelu(float x) {
    float x2 = x * x;
    float m  = x * __builtin_fmaf(x2, -0.10294314f, -2.30220795f);
    float e  = __builtin_amdgcn_exp2f(m);
    return x * __builtin_amdgcn_rcpf(1.0f + e);
}

// ---------------- aux kernels ----------------

// 1024 blocks: [0,512) reduce |W1| -> part[b]; [512,1024) reduce |W2| -> part[b].
// No atomics, no zero-init needed (every slot written).
__global__ void abs_sum2_kernel(const float4* __restrict__ w0, const float4* __restrict__ w1,
                                int n4, float* __restrict__ part) {
    int half = (int)blockIdx.x >> 9;
    const float4* w = half ? w1 : w0;
    int b = (int)blockIdx.x & 511;
    float s = 0.0f;
    for (int i = b * blockDim.x + threadIdx.x; i < n4; i += 512 * blockDim.x) {
        float4 v = w[i];
        s += fabsf(v.x) + fabsf(v.y) + fabsf(v.z) + fabsf(v.w);
    }
    #pragma unroll
    for (int o = 32; o > 0; o >>= 1) s += __shfl_down(s, o, 64);
    __shared__ float ps[4];
    int lane = threadIdx.x & 63, wid = threadIdx.x >> 6;
    if (lane == 0) ps[wid] = s;
    __syncthreads();
    if (threadIdx.x == 0) part[blockIdx.x] = ps[0] + ps[1] + ps[2] + ps[3];
}

// 2048 blocks: [0,1024) ternarize W1 -> t0; [1024,2048) ternarize W2 -> t1.
// Each block first reduces its segment's 512 partials (L2-hot).
__global__ void ternarize_kernel(const float4* __restrict__ w0, ushort4* __restrict__ t0,
                                 const float4* __restrict__ w1, ushort4* __restrict__ t1,
                                 int n4w, const float* __restrict__ part, float inv_n) {
    int seg = (int)blockIdx.x >> 10;               // 0 or 1
    int b = (int)blockIdx.x & 1023;

    // block-reduce 512 partials -> scale (identical in every block of a segment)
    float s = 0.0f;
    for (int j = threadIdx.x; j < 512; j += 256) s += part[seg * 512 + j];
    #pragma unroll
    for (int o = 32; o > 0; o >>= 1) s += __shfl_down(s, o, 64);
    __shared__ float ps[4];
    __shared__ float sscale;
    int lane = threadIdx.x & 63, wid = threadIdx.x >> 6;
    if (lane == 0) ps[wid] = s;
    __syncthreads();
    if (threadIdx.x == 0) {
        float tot = ps[0] + ps[1] + ps[2] + ps[3];
        sscale = fmaxf(tot * inv_n, 1e-8f);
    }
    __syncthreads();
    float inv = 1.0f / sscale;

    const float4* w = seg ? w1 : w0;
    ushort4* t = seg ? t1 : t0;
    for (int i = b * blockDim.x + threadIdx.x; i < n4w; i += 1024 * blockDim.x) {
        float4 v = w[i];
        ushort4 o;
        o.x = f2bf(fminf(fmaxf(rintf(v.x * inv), -1.0f), 1.0f));
        o.y = f2bf(fminf(fmaxf(rintf(v.y * inv), -1.0f), 1.0f));
        o.z = f2bf(fminf(fmaxf(rintf(v.z * inv), -1.0f), 1.0f));
        o.w = f2bf(fminf(fmaxf(rintf(v.w * inv), -1.0f), 1.0f));
        t[i] = o;
    }
}

// ---------------- GEMM1: h = gelu(x * W1^T + b1), A = fp32 x converted in-kernel ----
// BM=BN=128, BK=64; 256 threads = 4 waves, wave tile 64x64 (4x4 of 16x16x32 MFMA).
// LDS XOR-swizzled in 16B chunks: physical chunk = logical ^ (row&7).
// A: fp32 global -> VGPR -> bf16 -> ds_write_b128 (swizzle in LDS address).
// B: bf16 global_load_lds (swizzle folded into global source column).

template <int K, int N>   // K=1024, N=4096
__global__ __launch_bounds__(256)
void gemm1_kernel(const float* __restrict__ X,
                  const unsigned short* __restrict__ B,
                  const float* __restrict__ bias,
                  unsigned short* __restrict__ C) {
    __shared__ __align__(16) unsigned short As[128 * 64];
    __shared__ __align__(16) unsigned short Bs[128 * 64];

    const int tid  = threadIdx.x;
    const int lane = tid & 63;
    const int wid  = tid >> 6;
    const int mBase = (wid >> 1) * 64;
    const int nBase = (wid & 1) * 64;
    const int lr = lane & 15;
    const int lq = lane >> 4;

    const size_t aRow0 = (size_t)blockIdx.y * 128;
    const size_t bRow0 = (size_t)blockIdx.x * 128;

    const int rA = tid >> 3;                 // 0..31
    const int cA = tid & 7;                  // logical 16B chunk
    const int pA = cA ^ (rA & 7);            // physical chunk (swizzle)
    const float* gx = X + (aRow0 + rA) * (size_t)K + cA * 8;     // fp32 source
    const unsigned short* gb = B + (bRow0 + rA) * (size_t)K + pA * 8; // swizzled col
    unsigned short* ldsAw = &As[rA * 64 + pA * 8];
    unsigned short* ldsB  = &Bs[tid * 8];

    f32x4 acc[4][4];
    #pragma unroll
    for (int i = 0; i < 4; ++i)
        #pragma unroll
        for (int j = 0; j < 4; ++j)
            acc[i][j] = f32x4{0.f, 0.f, 0.f, 0.f};

    const int swz0 = ((lq ^ (lr & 7)) << 3);
    const int swz1 = (((4 + lq) ^ (lr & 7)) << 3);

    for (int k0 = 0; k0 < K; k0 += 64) {
        __syncthreads();
        // B: async direct-to-LDS
        #pragma unroll
        for (int t = 0; t < 4; ++t)
            __builtin_amdgcn_global_load_lds(
                (const __attribute__((address_space(1))) void*)(gb + (size_t)t * 32 * K),
                (__attribute__((address_space(3))) void*)(ldsB + t * 2048), 16, 0, 0);
        gb += 64;
        // A: fp32 -> bf16 via VGPR (issue all loads first)
        f32x4 lo[4], hi[4];
        #pragma unroll
        for (int t = 0; t < 4; ++t) {
            lo[t] = *(const f32x4*)(gx + (size_t)t * 32 * K);
            hi[t] = *(const f32x4*)(gx + (size_t)t * 32 * K + 4);
        }
        gx += 64;
        #pragma unroll
        for (int t = 0; t < 4; ++t) {
            us8 v;
            v[0] = f2bf(lo[t][0]); v[1] = f2bf(lo[t][1]);
            v[2] = f2bf(lo[t][2]); v[3] = f2bf(lo[t][3]);
            v[4] = f2bf(hi[t][0]); v[5] = f2bf(hi[t][1]);
            v[6] = f2bf(hi[t][2]); v[7] = f2bf(hi[t][3]);
            *(us8*)(ldsAw + t * 2048) = v;
        }
        __syncthreads();
        #pragma unroll
        for (int ks = 0; ks < 2; ++ks) {
            const int swz = ks ? swz1 : swz0;
            bf16x8 avec[4], bvec[4];
            #pragma unroll
            for (int i = 0; i < 4; ++i) {
                avec[i] = *(const bf16x8*)&As[(mBase + i * 16 + lr) * 64 + swz];
                bvec[i] = *(const bf16x8*)&Bs[(nBase + i * 16 + lr) * 64 + swz];
            }
            #pragma unroll
            for (int mi = 0; mi < 4; ++mi)
                #pragma unroll
                for (int ni = 0; ni < 4; ++ni)
                    acc[mi][ni] = __builtin_amdgcn_mfma_f32_16x16x32_bf16(
                        avec[mi], bvec[ni], acc[mi][ni], 0, 0, 0);
        }
    }

    // epilogue: bias + fast GELU -> bf16. C/D: col=lane&15, row=(lane>>4)*4+reg
    #pragma unroll
    for (int mi = 0; mi < 4; ++mi) {
        #pragma unroll
        for (int ni = 0; ni < 4; ++ni) {
            int col = (int)bRow0 + nBase + ni * 16 + lr;
            float bv = bias[col];
            #pragma unroll
            for (int r = 0; r < 4; ++r) {
                size_t row = aRow0 + mBase + mi * 16 + lq * 4 + r;
                C[row * (size_t)N + col] = f2bf(fast_gelu(acc[mi][ni][r] + bv));
            }
        }
    }
}

// ---------------- GEMM2 (NT, bf16 inputs, fp32 out + bias) ----------------

template <int K, int N>   // K=4096, N=1024
__global__ __launch_bounds__(256)
void gemm2_kernel(const unsigned short* __restrict__ A,
                  const unsigned short* __restrict__ B,
                  const float* __restrict__ bias,
                  float* __restrict__ C) {
    __shared__ __align__(16) unsigned short As[128 * 64];
    __shared__ __align__(16) unsigned short Bs[128 * 64];

    const int tid  = threadIdx.x;
    const int lane = tid & 63;
    const int wid  = tid >> 6;
    const int mBase = (wid >> 1) * 64;
    const int nBase = (wid & 1) * 64;
    const int lr = lane & 15;
    const int lq = lane >> 4;

    const size_t aRow0 = (size_t)blockIdx.y * 128;
    const size_t bRow0 = (size_t)blockIdx.x * 128;

    const int rA  = tid >> 3;
    const int cSw = (((tid & 7) ^ (rA & 7)) << 3);
    const unsigned short* ga = A + (aRow0 + rA) * (size_t)K + cSw;
    const unsigned short* gb = B + (bRow0 + rA) * (size_t)K + cSw;
    unsigned short* ldsA = &As[tid * 8];
    unsigned short* ldsB = &Bs[tid * 8];

    f32x4 acc[4][4];
    #pragma unroll
    for (int i = 0; i < 4; ++i)
        #pragma unroll
        for (int j = 0; j < 4; ++j)
            acc[i][j] = f32x4{0.f, 0.f, 0.f, 0.f};

    const int swz0 = ((lq ^ (lr & 7)) << 3);
    const int swz1 = (((4 + lq) ^ (lr & 7)) << 3);

    #pragma unroll 2
    for (int k0 = 0; k0 < K; k0 += 64) {
        __syncthreads();
        #pragma unroll
        for (int t = 0; t < 4; ++t) {
            __builtin_amdgcn_global_load_lds(
                (const __attribute__((address_space(1))) void*)(ga + (size_t)t * 32 * K),
                (__attribute__((address_space(3))) void*)(ldsA + t * 2048), 16, 0, 0);
            __builtin_amdgcn_global_load_lds(
                (const __attribute__((address_space(1))) void*)(gb + (size_t)t * 32 * K),
                (__attribute__((address_space(3))) void*)(ldsB + t * 2048), 16, 0, 0);
        }
        ga += 64;
        gb += 64;
        __syncthreads();
        #pragma unroll
        for (int ks = 0; ks < 2; ++ks) {
            const int swz = ks ? swz1 : swz0;
            bf16x8 avec[4], bvec[4];
            #pragma unroll
            for (int i = 0; i < 4; ++i) {
                avec[i] = *(const bf16x8*)&As[(mBase + i * 16 + lr) * 64 + swz];
                bvec[i] = *(const bf16x8*)&Bs[(nBase + i * 16 + lr) * 64 + swz];
            }
            #pragma unroll
            for (int mi = 0; mi < 4; ++mi)
                #pragma unroll
                for (int ni = 0; ni < 4; ++ni)
                    acc[mi][ni] = __builtin_amdgcn_mfma_f32_16x16x32_bf16(
                        avec[mi], bvec[ni], acc[mi][ni], 0, 0, 0);
        }
    }

    #pragma unroll
    for (int mi = 0; mi < 4; ++mi) {
        #pragma unroll
        for (int ni = 0; ni < 4; ++ni) {
            int col = (int)bRow0 + nBase + ni * 16 + lr;
            float bv = bias[col];
            #pragma unroll
            for (int r = 0; r < 4; ++r) {
                size_t row = aRow0 + mBase + mi * 16 + lq * 4 + r;
                C[row * (size_t)N + col] = acc[mi][ni][r] + bv;
            }
        }
    }
}

// ---------------- launch ----------------

extern "C" void kernel_launch(void* const* d_in, const int* in_sizes, int n_in,
                              void* d_out, int out_size, void* d_ws, size_t ws_size,
                              hipStream_t stream) {
    const float* x  = (const float*)d_in[0];   // [4,2048,1024]
    const float* W1 = (const float*)d_in[1];   // [4096,1024]
    const float* b1 = (const float*)d_in[2];   // [4096]
    const float* W2 = (const float*)d_in[3];   // [1024,4096]
    const float* b2 = (const float*)d_in[4];   // [1024]
    float* out = (float*)d_out;                // fp32 [4,2048,1024]

    const int M = 8192, EMB = 1024, FF = 4096;
    const int nW = FF * EMB;                   // 4194304

    char* ws = (char*)d_ws;
    float* part = (float*)ws;                                    // 1024 floats
    unsigned short* W1t = (unsigned short*)(ws + 16384);         // 8.39 MB
    unsigned short* W2t = W1t + (size_t)nW;                      // 8.39 MB
    unsigned short* h   = W2t + (size_t)nW;                      // 67.1 MB

    abs_sum2_kernel<<<1024, 256, 0, stream>>>((const float4*)W1, (const float4*)W2,
                                              nW / 4, part);
    ternarize_kernel<<<2048, 256, 0, stream>>>((const float4*)W1, (ushort4*)W1t,
                                               (const float4*)W2, (ushort4*)W2t,
                                               nW / 4, part, 1.0f / nW);

    // GEMM1: h[M,FF] = gelu(x[M,EMB] * W1t^T + b1), fp32 A converted in-kernel
    gemm1_kernel<1024, 4096><<<dim3(FF / 128, M / 128), 256, 0, stream>>>(x, W1t, b1, h);
    // GEMM2: out[M,EMB] = h[M,FF] * W2t^T + b2
    gemm2_kernel<4096, 1024><<<dim3(EMB / 128, M / 128), 256, 0, stream>>>(h, W2t, b2, out);
}

// Round 5
// 268.707 us; speedup vs baseline: 1.1748x; 1.1748x over previous
//
#include <hip/hip_runtime.h>
#include <hip/hip_bf16.h>
#include <cstdint>
#include <cstddef>

typedef __bf16 bf16x8 __attribute__((ext_vector_type(8)));
typedef float  f32x4  __attribute__((ext_vector_type(4)));

__device__ __forceinline__ unsigned short f2bf(float f) {
    __hip_bfloat16 b = __float2bfloat16(f);
    return *reinterpret_cast<unsigned short*>(&b);
}

// fast GELU (tanh form), ~7 VALU ops, saturation-safe:
// g = x / (1 + exp2(x*(-2.30220795 - 0.10294314 x^2)))
__device__ __forceinline__ float fast_gelu(float x) {
    float x2 = x * x;
    float m  = x * __builtin_fmaf(x2, -0.10294314f, -2.30220795f);
    float e  = __builtin_amdgcn_exp2f(m);
    return x * __builtin_amdgcn_rcpf(1.0f + e);
}

// ---------------- aux kernels ----------------

// 1536 blocks: [0,512) |W1|-partials; [512,1024) |W2|-partials; [1024,1536) x->bf16.
// The cvt segment is independent of the sums, so it rides in the same dispatch.
__global__ void abs_sum_cvt_kernel(const float4* __restrict__ w0, const float4* __restrict__ w1,
                                   int n4w, float* __restrict__ part,
                                   const float4* __restrict__ x, ushort4* __restrict__ xb,
                                   int n4x) {
    int seg = (int)blockIdx.x >> 9;                // 0,1,2
    int b = (int)blockIdx.x & 511;
    if (seg == 2) {
        for (int i = b * blockDim.x + threadIdx.x; i < n4x; i += 512 * blockDim.x) {
            float4 v = x[i];
            ushort4 o;
            o.x = f2bf(v.x); o.y = f2bf(v.y); o.z = f2bf(v.z); o.w = f2bf(v.w);
            xb[i] = o;
        }
        return;
    }
    const float4* w = seg ? w1 : w0;
    float s = 0.0f;
    for (int i = b * blockDim.x + threadIdx.x; i < n4w; i += 512 * blockDim.x) {
        float4 v = w[i];
        s += fabsf(v.x) + fabsf(v.y) + fabsf(v.z) + fabsf(v.w);
    }
    #pragma unroll
    for (int o = 32; o > 0; o >>= 1) s += __shfl_down(s, o, 64);
    __shared__ float ps[4];
    int lane = threadIdx.x & 63, wid = threadIdx.x >> 6;
    if (lane == 0) ps[wid] = s;
    __syncthreads();
    if (threadIdx.x == 0) part[blockIdx.x] = ps[0] + ps[1] + ps[2] + ps[3];
}

// 2048 blocks: [0,1024) ternarize W1 -> t0; [1024,2048) ternarize W2 -> t1.
// Each block first reduces its segment's 512 partials (L2-hot, ~2 µs).
__global__ void ternarize_kernel(const float4* __restrict__ w0, ushort4* __restrict__ t0,
                                 const float4* __restrict__ w1, ushort4* __restrict__ t1,
                                 int n4w, const float* __restrict__ part, float inv_n) {
    int seg = (int)blockIdx.x >> 10;               // 0 or 1
    int b = (int)blockIdx.x & 1023;

    float s = 0.0f;
    for (int j = threadIdx.x; j < 512; j += 256) s += part[seg * 512 + j];
    #pragma unroll
    for (int o = 32; o > 0; o >>= 1) s += __shfl_down(s, o, 64);
    __shared__ float ps[4];
    __shared__ float sscale;
    int lane = threadIdx.x & 63, wid = threadIdx.x >> 6;
    if (lane == 0) ps[wid] = s;
    __syncthreads();
    if (threadIdx.x == 0) {
        float tot = ps[0] + ps[1] + ps[2] + ps[3];
        sscale = fmaxf(tot * inv_n, 1e-8f);
    }
    __syncthreads();
    float inv = 1.0f / sscale;

    const float4* w = seg ? w1 : w0;
    ushort4* t = seg ? t1 : t0;
    for (int i = b * blockDim.x + threadIdx.x; i < n4w; i += 1024 * blockDim.x) {
        float4 v = w[i];
        ushort4 o;
        o.x = f2bf(fminf(fmaxf(rintf(v.x * inv), -1.0f), 1.0f));
        o.y = f2bf(fminf(fmaxf(rintf(v.y * inv), -1.0f), 1.0f));
        o.z = f2bf(fminf(fmaxf(rintf(v.z * inv), -1.0f), 1.0f));
        o.w = f2bf(fminf(fmaxf(rintf(v.w * inv), -1.0f), 1.0f));
        t[i] = o;
    }
}

// ---------------- GEMM (NT: C[m][n] = sum_k A[m][k]*B[n][k]) ----------------
// R3-proven structure: BM=BN=128, BK=64; 256 threads = 4 waves, wave tile 64x64
// (4x4 of 16x16x32 MFMA). Both A and B staged via global_load_lds (16B/lane,
// fire-and-forget — do NOT route staging through VGPRs, it drains vmcnt and
// serializes the pipeline; measured 89 -> 146 µs regression in R4).
// LDS XOR-swizzled in 16B chunks (physical chunk = logical ^ (row&7)), applied
// by permuting the GLOBAL source column per lane. Zero bank conflicts (R2).
// K, N compile-time powers of 2 -> all shifts, staging ptrs strength-reduced.
// EPI==0: C = bf16, bias + fast GELU.  EPI==1: C = fp32, bias.

template <int EPI, int K, int N>
__global__ __launch_bounds__(256)
void gemm_bt_kernel(const unsigned short* __restrict__ A,
                    const unsigned short* __restrict__ B,
                    const float* __restrict__ bias,
                    void* __restrict__ C) {
    __shared__ __align__(16) unsigned short As[128 * 64];
    __shared__ __align__(16) unsigned short Bs[128 * 64];

    const int tid  = threadIdx.x;
    const int lane = tid & 63;
    const int wid  = tid >> 6;
    const int mBase = (wid >> 1) * 64;
    const int nBase = (wid & 1) * 64;
    const int lr = lane & 15;
    const int lq = lane >> 4;

    const size_t aRow0 = (size_t)blockIdx.y * 128;
    const size_t bRow0 = (size_t)blockIdx.x * 128;

    const int rA  = tid >> 3;
    const int cSw = (((tid & 7) ^ (rA & 7)) << 3);
    const unsigned short* ga = A + (aRow0 + rA) * (size_t)K + cSw;
    const unsigned short* gb = B + (bRow0 + rA) * (size_t)K + cSw;
    unsigned short* ldsA = &As[tid * 8];
    unsigned short* ldsB = &Bs[tid * 8];

    f32x4 acc[4][4];
    #pragma unroll
    for (int i = 0; i < 4; ++i)
        #pragma unroll
        for (int j = 0; j < 4; ++j)
            acc[i][j] = f32x4{0.f, 0.f, 0.f, 0.f};

    const int swz0 = ((lq ^ (lr & 7)) << 3);
    const int swz1 = (((4 + lq) ^ (lr & 7)) << 3);

    #pragma unroll 2
    for (int k0 = 0; k0 < K; k0 += 64) {
        __syncthreads();
        #pragma unroll
        for (int t = 0; t < 4; ++t) {
            __builtin_amdgcn_global_load_lds(
                (const __attribute__((address_space(1))) void*)(ga + (size_t)t * 32 * K),
                (__attribute__((address_space(3))) void*)(ldsA + t * 2048), 16, 0, 0);
            __builtin_amdgcn_global_load_lds(
                (const __attribute__((address_space(1))) void*)(gb + (size_t)t * 32 * K),
                (__attribute__((address_space(3))) void*)(ldsB + t * 2048), 16, 0, 0);
        }
        ga += 64;
        gb += 64;
        __syncthreads();
        #pragma unroll
        for (int ks = 0; ks < 2; ++ks) {
            const int swz = ks ? swz1 : swz0;
            bf16x8 avec[4], bvec[4];
            #pragma unroll
            for (int i = 0; i < 4; ++i) {
                avec[i] = *(const bf16x8*)&As[(mBase + i * 16 + lr) * 64 + swz];
                bvec[i] = *(const bf16x8*)&Bs[(nBase + i * 16 + lr) * 64 + swz];
            }
            #pragma unroll
            for (int mi = 0; mi < 4; ++mi)
                #pragma unroll
                for (int ni = 0; ni < 4; ++ni)
                    acc[mi][ni] = __builtin_amdgcn_mfma_f32_16x16x32_bf16(
                        avec[mi], bvec[ni], acc[mi][ni], 0, 0, 0);
        }
    }

    // epilogue. C/D layout: col = lane&15, row = (lane>>4)*4 + reg
    #pragma unroll
    for (int mi = 0; mi < 4; ++mi) {
        #pragma unroll
        for (int ni = 0; ni < 4; ++ni) {
            int col = (int)bRow0 + nBase + ni * 16 + lr;
            float bv = bias[col];
            #pragma unroll
            for (int r = 0; r < 4; ++r) {
                size_t row = aRow0 + mBase + mi * 16 + lq * 4 + r;
                float v = acc[mi][ni][r] + bv;
                if (EPI == 0) {
                    ((unsigned short*)C)[row * (size_t)N + col] = f2bf(fast_gelu(v));
                } else {
                    ((float*)C)[row * (size_t)N + col] = v;
                }
            }
        }
    }
}

// ---------------- launch ----------------

extern "C" void kernel_launch(void* const* d_in, const int* in_sizes, int n_in,
                              void* d_out, int out_size, void* d_ws, size_t ws_size,
                              hipStream_t stream) {
    const float* x  = (const float*)d_in[0];   // [4,2048,1024]
    const float* W1 = (const float*)d_in[1];   // [4096,1024]
    const float* b1 = (const float*)d_in[2];   // [4096]
    const float* W2 = (const float*)d_in[3];   // [1024,4096]
    const float* b2 = (const float*)d_in[4];   // [1024]
    float* out = (float*)d_out;                // fp32 [4,2048,1024]

    const int M = 8192, EMB = 1024, FF = 4096;
    const int nW = FF * EMB;                   // 4194304

    char* ws = (char*)d_ws;
    float* part = (float*)ws;                                    // 1024 floats
    unsigned short* W1t = (unsigned short*)(ws + 16384);         // 8.39 MB
    unsigned short* W2t = W1t + (size_t)nW;                      // 8.39 MB
    unsigned short* xb  = W2t + (size_t)nW;                      // 16.78 MB
    unsigned short* h   = xb  + (size_t)M * EMB;                 // 67.1 MB

    abs_sum_cvt_kernel<<<1536, 256, 0, stream>>>((const float4*)W1, (const float4*)W2,
                                                 nW / 4, part,
                                                 (const float4*)x, (ushort4*)xb,
                                                 (M * EMB) / 4);
    ternarize_kernel<<<2048, 256, 0, stream>>>((const float4*)W1, (ushort4*)W1t,
                                               (const float4*)W2, (ushort4*)W2t,
                                               nW / 4, part, 1.0f / nW);

    // GEMM1: h[M,FF] = gelu(x[M,EMB] * W1t^T + b1), bf16 out
    gemm_bt_kernel<0, 1024, 4096><<<dim3(FF / 128, M / 128), 256, 0, stream>>>(xb, W1t, b1, h);
    // GEMM2: out[M,EMB] = h[M,FF] * W2t^T + b2, fp32 out
    gemm_bt_kernel<1, 4096, 1024><<<dim3(EMB / 128, M / 128), 256, 0, stream>>>(h, W2t, b2, out);
}